// Round 11
// baseline (81.617 us; speedup 1.0000x reference)
//
#include <hip/hip_runtime.h>
#include <cstdint>
#include <cstddef>

#define N 8192
#define IN_F 256
#define OUT_F 128
#define ALPHA 0.2f
typedef unsigned long long ull;
typedef float f32x4 __attribute__((ext_vector_type(4)));

__device__ __forceinline__ float bf2f(unsigned short u) {
    return __uint_as_float(((unsigned)u) << 16);
}
__device__ __forceinline__ unsigned short f2bf(float f) {
    unsigned x = __float_as_uint(f);
    unsigned r = (x + 0x7FFFu + ((x >> 16) & 1u)) >> 16;   // round-nearest-even
    return (unsigned short)r;
}

// ---------------------------------------------------------------------------
// Kernel 1: h = x @ W (bf16 out), fused s1 = h.a1, s2 = h.a2 (fp32).
// grid 512 (M=16 rows/block), 256 threads, BK=64, thread tile 2 rows x 4 cols.
// (unchanged from R9)
// ---------------------------------------------------------------------------
__global__ __launch_bounds__(256) void gemm_xw(const float* __restrict__ x,
                                               const float* __restrict__ W,
                                               const float* __restrict__ a,
                                               unsigned short* __restrict__ hb,
                                               float* __restrict__ s1,
                                               float* __restrict__ s2) {
    __shared__ __align__(16) float xsT[64 * 20];    // [kk][r], pad stride 20
    __shared__ __align__(16) float ws[64 * 128];    // [kk][o]
    const int tid = threadIdx.x;
    const int R0  = blockIdx.x * 16;
    const int r0  = (tid >> 5) * 2;   // 0..14
    const int c0  = (tid & 31) * 4;   // 0..124

    float acc[2][4];
#pragma unroll
    for (int r = 0; r < 2; ++r)
#pragma unroll
        for (int c = 0; c < 4; ++c) acc[r][c] = 0.f;

    for (int k0 = 0; k0 < IN_F; k0 += 64) {
        {
            const int r  = tid >> 4;         // 0..15
            const int k4 = tid & 15;         // 0..15
            const float4 v = *(const float4*)(x + (size_t)(R0 + r) * IN_F + k0 + k4 * 4);
            xsT[(k4 * 4 + 0) * 20 + r] = v.x;
            xsT[(k4 * 4 + 1) * 20 + r] = v.y;
            xsT[(k4 * 4 + 2) * 20 + r] = v.z;
            xsT[(k4 * 4 + 3) * 20 + r] = v.w;
        }
#pragma unroll
        for (int q = 0; q < 8; ++q) {
            const int f = tid + q * 256;
            *(float4*)(ws + f * 4) = *(const float4*)(W + (size_t)k0 * OUT_F + f * 4);
        }
        __syncthreads();

#pragma unroll 8
        for (int kk = 0; kk < 64; ++kk) {
            const float4 wv = *(const float4*)(ws + kk * 128 + c0);
            const float2 xv = *(const float2*)(xsT + kk * 20 + r0);
            acc[0][0] += xv.x * wv.x; acc[0][1] += xv.x * wv.y; acc[0][2] += xv.x * wv.z; acc[0][3] += xv.x * wv.w;
            acc[1][0] += xv.y * wv.x; acc[1][1] += xv.y * wv.y; acc[1][2] += xv.y * wv.z; acc[1][3] += xv.y * wv.w;
        }
        __syncthreads();
    }

#pragma unroll
    for (int r = 0; r < 2; ++r) {
        ushort4 o4;
        o4.x = f2bf(acc[r][0]); o4.y = f2bf(acc[r][1]);
        o4.z = f2bf(acc[r][2]); o4.w = f2bf(acc[r][3]);
        *(ushort4*)(hb + (size_t)(R0 + r0 + r) * OUT_F + c0) = o4;
    }

    const float4 a1v = *(const float4*)(a + c0);
    const float4 a2v = *(const float4*)(a + OUT_F + c0);
#pragma unroll
    for (int r = 0; r < 2; ++r) {
        float p1 = acc[r][0] * a1v.x + acc[r][1] * a1v.y + acc[r][2] * a1v.z + acc[r][3] * a1v.w;
        float p2 = acc[r][0] * a2v.x + acc[r][1] * a2v.y + acc[r][2] * a2v.z + acc[r][3] * a2v.w;
#pragma unroll
        for (int off = 16; off > 0; off >>= 1) {
            p1 += __shfl_xor(p1, off);
            p2 += __shfl_xor(p2, off);
        }
        if ((tid & 31) == 0) {
            s1[R0 + r0 + r] = p1;
            s2[R0 + r0 + r] = p2;
        }
    }
}

// ---------------------------------------------------------------------------
// Kernel 2: single-pass fused row processing. One wave = one row; NO phases.
// Max-free softmax (validated R10): per ballot-hit j, immediately
//   w = exp(lrelu(s1[i] + s2_lds[j]));  acc += w * h[j];  dp += w
// so gather loads interleave with the adj stream — no list, no decode, no
// convoy. s2 staged in LDS once per 512-thread block (32 KB -> 4 blocks/CU,
// 32 waves/CU). Each lane owns output cols {2*lane, 2*lane+1} (bf16x2 = 4B
// per lane per hit, 256 B/wave, coalesced L2 hit).
// grid 1024 x 512 (8 waves = 8 rows per block).
// ---------------------------------------------------------------------------
__global__ __launch_bounds__(512, 8) void gat_fused(const float* __restrict__ adj,
                                                    const unsigned* __restrict__ hb32,
                                                    const float* __restrict__ s1,
                                                    const float* __restrict__ s2,
                                                    float* __restrict__ out) {
    const int tid  = threadIdx.x;
    const int wv   = tid >> 6;
    const int lane = tid & 63;
    const int row  = blockIdx.x * 8 + wv;

    __shared__ __align__(16) float s2l[N];   // 32 KB

    // stage s2: 8192 floats / 512 threads = 4 float4 each
#pragma unroll
    for (int q = 0; q < 4; ++q) {
        const int idx = tid + q * 512;                 // float4 index 0..2047
        *(float4*)(s2l + idx * 4) = *(const float4*)(s2 + idx * 4);
    }
    __syncthreads();

    const float si = s1[row];
    const f32x4* __restrict__ arow = (const f32x4*)(adj + (size_t)row * N);

    float acc0 = 0.f, acc1 = 0.f, dp = 0.f;

    // 32 float4 per lane, 4-deep prefetch ring
    f32x4 va[4], vb[4];
#pragma unroll
    for (int u = 0; u < 4; ++u) va[u] = arow[lane + u * 64];

    for (int b = 0; b < 8; ++b) {
        if (b < 7) {
#pragma unroll
            for (int u = 0; u < 4; ++u) vb[u] = arow[lane + ((b + 1) * 4 + u) * 64];
        }
#pragma unroll
        for (int u = 0; u < 4; ++u) {
            const int base = (b * 4 + u) * 256;        // chunk of 256 elems
            const float av[4] = {va[u].x, va[u].y, va[u].z, va[u].w};
#pragma unroll
            for (int c = 0; c < 4; ++c) {
                ull m = __ballot(av[c] > 0.f);
                while (m) {                            // wave-uniform loop
                    const int bt = __builtin_ctzll(m);
                    m &= m - 1;
                    const int j = base + 4 * bt + c;
                    float e = si + s2l[j];
                    e = e > 0.f ? e : ALPHA * e;
                    const float w = __expf(e);
                    const unsigned hv = hb32[j * 64 + lane];
                    acc0 += w * bf2f((unsigned short)(hv & 0xFFFFu));
                    acc1 += w * bf2f((unsigned short)(hv >> 16));
                    dp += w;
                }
            }
        }
#pragma unroll
        for (int u = 0; u < 4; ++u) va[u] = vb[u];
    }

    // dp is identical across lanes (w was uniform per hit) — no reduction.
    const float r = 1.f / dp;
    float v0 = acc0 * r, v1 = acc1 * r;
    float2 o;
    o.x = v0 > 0.f ? v0 : (__expf(v0) - 1.f);
    o.y = v1 > 0.f ? v1 : (__expf(v1) - 1.f);
    *(float2*)(out + (size_t)row * OUT_F + 2 * lane) = o;
}

// ---------------------------------------------------------------------------
extern "C" void kernel_launch(void* const* d_in, const int* in_sizes, int n_in,
                              void* d_out, int out_size, void* d_ws, size_t ws_size,
                              hipStream_t stream) {
    const float* x   = (const float*)d_in[0];   // (8192, 256)
    const float* adj = (const float*)d_in[1];   // (8192, 8192)
    const float* W   = (const float*)d_in[2];   // (256, 128)
    const float* a   = (const float*)d_in[3];   // (256, 1)
    float* out = (float*)d_out;                 // (8192, 128) fp32

    char* wsb = (char*)d_ws;
    unsigned short* hb = (unsigned short*)wsb;                    // 2 MB bf16 h
    float* s1 = (float*)(wsb + 2 * 1024 * 1024);                  // 32 KB
    float* s2 = s1 + N;                                           // 32 KB

    gemm_xw<<<N / 16, 256, 0, stream>>>(x, W, a, hb, s1, s2);
    gat_fused<<<1024, 512, 0, stream>>>(adj, (const unsigned*)hb, s1, s2, out);
}

// Round 12
// 73.536 us; speedup vs baseline: 1.1099x; 1.1099x over previous
//
#include <hip/hip_runtime.h>
#include <cstdint>
#include <cstddef>

#define N 8192
#define IN_F 256
#define OUT_F 128
#define ALPHA 0.2f
#define CAP 256
typedef unsigned long long ull;
typedef float f32x4 __attribute__((ext_vector_type(4)));

__device__ __forceinline__ float bf2f(unsigned short u) {
    return __uint_as_float(((unsigned)u) << 16);
}
__device__ __forceinline__ unsigned short f2bf(float f) {
    unsigned x = __float_as_uint(f);
    unsigned r = (x + 0x7FFFu + ((x >> 16) & 1u)) >> 16;   // round-nearest-even
    return (unsigned short)r;
}

// ---------------------------------------------------------------------------
// Kernel 1: h = x @ W (bf16 out), fused s1 = h.a1, s2 = h.a2 (fp32).
// grid 512 (M=16 rows/block), 256 threads, BK=64, thread tile 2 rows x 4 cols.
// (unchanged from R6)
// ---------------------------------------------------------------------------
__global__ __launch_bounds__(256) void gemm_xw(const float* __restrict__ x,
                                               const float* __restrict__ W,
                                               const float* __restrict__ a,
                                               unsigned short* __restrict__ hb,
                                               float* __restrict__ s1,
                                               float* __restrict__ s2) {
    __shared__ __align__(16) float xsT[64 * 20];    // [kk][r], pad stride 20
    __shared__ __align__(16) float ws[64 * 128];    // [kk][o]
    const int tid = threadIdx.x;
    const int R0  = blockIdx.x * 16;
    const int r0  = (tid >> 5) * 2;   // 0..14
    const int c0  = (tid & 31) * 4;   // 0..124

    float acc[2][4];
#pragma unroll
    for (int r = 0; r < 2; ++r)
#pragma unroll
        for (int c = 0; c < 4; ++c) acc[r][c] = 0.f;

    for (int k0 = 0; k0 < IN_F; k0 += 64) {
        {
            const int r  = tid >> 4;         // 0..15
            const int k4 = tid & 15;         // 0..15
            const float4 v = *(const float4*)(x + (size_t)(R0 + r) * IN_F + k0 + k4 * 4);
            xsT[(k4 * 4 + 0) * 20 + r] = v.x;
            xsT[(k4 * 4 + 1) * 20 + r] = v.y;
            xsT[(k4 * 4 + 2) * 20 + r] = v.z;
            xsT[(k4 * 4 + 3) * 20 + r] = v.w;
        }
#pragma unroll
        for (int q = 0; q < 8; ++q) {
            const int f = tid + q * 256;
            *(float4*)(ws + f * 4) = *(const float4*)(W + (size_t)k0 * OUT_F + f * 4);
        }
        __syncthreads();

#pragma unroll 8
        for (int kk = 0; kk < 64; ++kk) {
            const float4 wv = *(const float4*)(ws + kk * 128 + c0);
            const float2 xv = *(const float2*)(xsT + kk * 20 + r0);
            acc[0][0] += xv.x * wv.x; acc[0][1] += xv.x * wv.y; acc[0][2] += xv.x * wv.z; acc[0][3] += xv.x * wv.w;
            acc[1][0] += xv.y * wv.x; acc[1][1] += xv.y * wv.y; acc[1][2] += xv.y * wv.z; acc[1][3] += xv.y * wv.w;
        }
        __syncthreads();
    }

#pragma unroll
    for (int r = 0; r < 2; ++r) {
        ushort4 o4;
        o4.x = f2bf(acc[r][0]); o4.y = f2bf(acc[r][1]);
        o4.z = f2bf(acc[r][2]); o4.w = f2bf(acc[r][3]);
        *(ushort4*)(hb + (size_t)(R0 + r0 + r) * OUT_F + c0) = o4;
    }

    const float4 a1v = *(const float4*)(a + c0);
    const float4 a2v = *(const float4*)(a + OUT_F + c0);
#pragma unroll
    for (int r = 0; r < 2; ++r) {
        float p1 = acc[r][0] * a1v.x + acc[r][1] * a1v.y + acc[r][2] * a1v.z + acc[r][3] * a1v.w;
        float p2 = acc[r][0] * a2v.x + acc[r][1] * a2v.y + acc[r][2] * a2v.z + acc[r][3] * a2v.w;
#pragma unroll
        for (int off = 16; off > 0; off >>= 1) {
            p1 += __shfl_xor(p1, off);
            p2 += __shfl_xor(p2, off);
        }
        if ((tid & 31) == 0) {
            s1[R0 + r0 + r] = p1;
            s2[R0 + r0 + r] = p2;
        }
    }
}

// ---------------------------------------------------------------------------
// Kernel 2: R6's fused per-wave kernel, ONE change: adj loads are
// NON-TEMPORAL (no L2 allocation). adj has zero reuse; keeping it out of L2
// preserves hb (2 MB) residency for the interleaved gathers, and may lift
// raw stream BW. hb loads remain cached.
// grid 2048 x 256 (4 waves = 4 rows / block), all 8192 waves co-resident.
// ---------------------------------------------------------------------------
__global__ __launch_bounds__(256, 8) void gat_fused(const float* __restrict__ adj,
                                                    const unsigned short* __restrict__ hb,
                                                    const float* __restrict__ s1,
                                                    const float* __restrict__ s2,
                                                    float* __restrict__ out) {
    const int tid  = threadIdx.x;
    const int wv   = tid >> 6;
    const int lane = tid & 63;
    const int row  = blockIdx.x * 4 + wv;

    __shared__ int   jl[4][CAP];
    __shared__ float el[4][CAP];

    const f32x4* __restrict__ arow = (const f32x4*)(adj + (size_t)row * N);
    const ull below = (1ull << lane) - 1ull;

    // ---- phase 1: scan 2048 float4 / 64 lanes = 32 per lane, batches of 4
    int tot = 0;
    f32x4 va[4], vb[4];
#pragma unroll
    for (int u = 0; u < 4; ++u) va[u] = __builtin_nontemporal_load(arow + lane + u * 64);

    for (int b = 0; b < 8; ++b) {
        if (b < 7) {
#pragma unroll
            for (int u = 0; u < 4; ++u)
                vb[u] = __builtin_nontemporal_load(arow + lane + ((b + 1) * 4 + u) * 64);
        }
#pragma unroll
        for (int u = 0; u < 4; ++u) {
            const int jb = (((b * 4 + u) * 64) + lane) * 4;
            const float av[4] = {va[u].x, va[u].y, va[u].z, va[u].w};
#pragma unroll
            for (int c = 0; c < 4; ++c) {
                const bool hit = av[c] > 0.f;
                const ull m = __ballot(hit);
                if (m) {                       // wave-uniform
                    const int base = tot;
                    tot += __popcll(m);
                    if (hit) {
                        const int p = base + __popcll(m & below);
                        if (p < CAP) jl[wv][p] = jb + c;
                    }
                }
            }
        }
#pragma unroll
        for (int u = 0; u < 4; ++u) va[u] = vb[u];
    }
    const int n = tot < CAP ? tot : CAP;

    // ---- phase 2: softmax over the list (<=4 entries per lane)
    const float si = s1[row];
    float ev[4];
    float lmax = -1e30f;
#pragma unroll
    for (int t = 0; t < 4; ++t) {
        const int l = lane + t * 64;
        float e = -1e30f;
        if (l < n) {
            e = si + s2[jl[wv][l]];
            e = e > 0.f ? e : ALPHA * e;
        }
        ev[t] = e;
        lmax = fmaxf(lmax, e);
    }
#pragma unroll
    for (int off = 32; off > 0; off >>= 1) lmax = fmaxf(lmax, __shfl_xor(lmax, off));

    float dp = 0.f;
#pragma unroll
    for (int t = 0; t < 4; ++t) {
        const int l = lane + t * 64;
        if (l < n) {
            const float wgt = __expf(ev[t] - lmax);
            el[wv][l] = wgt;
            dp += wgt;
        }
    }
#pragma unroll
    for (int off = 32; off > 0; off >>= 1) dp += __shfl_xor(dp, off);
    const float denom = dp;

    // ---- phase 3: gather; lane halves take even/odd entries, 32 lanes x 4 cols
    const int half = lane >> 5;
    const int col4 = (lane & 31) * 4;
    float a0 = 0.f, a1 = 0.f, a2 = 0.f, a3 = 0.f;
#pragma unroll 4
    for (int l = half; l < n; l += 2) {
        const float wgt = el[wv][l];
        const int j = jl[wv][l];
        const ushort4 hv = *(const ushort4*)(hb + (size_t)j * OUT_F + col4);
        a0 += wgt * bf2f(hv.x);
        a1 += wgt * bf2f(hv.y);
        a2 += wgt * bf2f(hv.z);
        a3 += wgt * bf2f(hv.w);
    }
    a0 += __shfl_xor(a0, 32);
    a1 += __shfl_xor(a1, 32);
    a2 += __shfl_xor(a2, 32);
    a3 += __shfl_xor(a3, 32);

    if (half == 0) {
        const float r = 1.f / denom;
        float v0 = a0 * r, v1 = a1 * r, v2 = a2 * r, v3 = a3 * r;
        float4 o;
        o.x = v0 > 0.f ? v0 : (__expf(v0) - 1.f);
        o.y = v1 > 0.f ? v1 : (__expf(v1) - 1.f);
        o.z = v2 > 0.f ? v2 : (__expf(v2) - 1.f);
        o.w = v3 > 0.f ? v3 : (__expf(v3) - 1.f);
        *(float4*)(out + (size_t)row * OUT_F + col4) = o;
    }
}

// ---------------------------------------------------------------------------
extern "C" void kernel_launch(void* const* d_in, const int* in_sizes, int n_in,
                              void* d_out, int out_size, void* d_ws, size_t ws_size,
                              hipStream_t stream) {
    const float* x   = (const float*)d_in[0];   // (8192, 256)
    const float* adj = (const float*)d_in[1];   // (8192, 8192)
    const float* W   = (const float*)d_in[2];   // (256, 128)
    const float* a   = (const float*)d_in[3];   // (256, 1)
    float* out = (float*)d_out;                 // (8192, 128) fp32

    char* wsb = (char*)d_ws;
    unsigned short* hb = (unsigned short*)wsb;                    // 2 MB bf16 h
    float* s1 = (float*)(wsb + 2 * 1024 * 1024);                  // 32 KB
    float* s2 = s1 + N;                                           // 32 KB

    gemm_xw<<<N / 16, 256, 0, stream>>>(x, W, a, hb, s1, s2);
    gat_fused<<<2048, 256, 0, stream>>>(adj, hb, s1, s2, out);
}

// Round 13
// 72.687 us; speedup vs baseline: 1.1229x; 1.0117x over previous
//
#include <hip/hip_runtime.h>
#include <cstdint>
#include <cstddef>

#define N 8192
#define IN_F 256
#define OUT_F 128
#define ALPHA 0.2f
#define QCAP 128          // per (row, srcwave) segment cap; mean 20.5, +24 sigma
typedef unsigned long long ull;
typedef float f32x4 __attribute__((ext_vector_type(4)));

__device__ __forceinline__ float bf2f(unsigned short u) {
    return __uint_as_float(((unsigned)u) << 16);
}
__device__ __forceinline__ unsigned short f2bf(float f) {
    unsigned x = __float_as_uint(f);
    unsigned r = (x + 0x7FFFu + ((x >> 16) & 1u)) >> 16;   // round-nearest-even
    return (unsigned short)r;
}

// ---------------------------------------------------------------------------
// Kernel 1: h = x @ W (bf16 out), fused s1 = h.a1, s2 = h.a2 (fp32).
// grid 512 (M=16 rows/block), 256 threads, BK=64, thread tile 2 rows x 4 cols.
// (unchanged from R6)
// ---------------------------------------------------------------------------
__global__ __launch_bounds__(256) void gemm_xw(const float* __restrict__ x,
                                               const float* __restrict__ W,
                                               const float* __restrict__ a,
                                               unsigned short* __restrict__ hb,
                                               float* __restrict__ s1,
                                               float* __restrict__ s2) {
    __shared__ __align__(16) float xsT[64 * 20];    // [kk][r], pad stride 20
    __shared__ __align__(16) float ws[64 * 128];    // [kk][o]
    const int tid = threadIdx.x;
    const int R0  = blockIdx.x * 16;
    const int r0  = (tid >> 5) * 2;   // 0..14
    const int c0  = (tid & 31) * 4;   // 0..124

    float acc[2][4];
#pragma unroll
    for (int r = 0; r < 2; ++r)
#pragma unroll
        for (int c = 0; c < 4; ++c) acc[r][c] = 0.f;

    for (int k0 = 0; k0 < IN_F; k0 += 64) {
        {
            const int r  = tid >> 4;         // 0..15
            const int k4 = tid & 15;         // 0..15
            const float4 v = *(const float4*)(x + (size_t)(R0 + r) * IN_F + k0 + k4 * 4);
            xsT[(k4 * 4 + 0) * 20 + r] = v.x;
            xsT[(k4 * 4 + 1) * 20 + r] = v.y;
            xsT[(k4 * 4 + 2) * 20 + r] = v.z;
            xsT[(k4 * 4 + 3) * 20 + r] = v.w;
        }
#pragma unroll
        for (int q = 0; q < 8; ++q) {
            const int f = tid + q * 256;
            *(float4*)(ws + f * 4) = *(const float4*)(W + (size_t)k0 * OUT_F + f * 4);
        }
        __syncthreads();

#pragma unroll 8
        for (int kk = 0; kk < 64; ++kk) {
            const float4 wv = *(const float4*)(ws + kk * 128 + c0);
            const float2 xv = *(const float2*)(xsT + kk * 20 + r0);
            acc[0][0] += xv.x * wv.x; acc[0][1] += xv.x * wv.y; acc[0][2] += xv.x * wv.z; acc[0][3] += xv.x * wv.w;
            acc[1][0] += xv.y * wv.x; acc[1][1] += xv.y * wv.y; acc[1][2] += xv.y * wv.z; acc[1][3] += xv.y * wv.w;
        }
        __syncthreads();
    }

#pragma unroll
    for (int r = 0; r < 2; ++r) {
        ushort4 o4;
        o4.x = f2bf(acc[r][0]); o4.y = f2bf(acc[r][1]);
        o4.z = f2bf(acc[r][2]); o4.w = f2bf(acc[r][3]);
        *(ushort4*)(hb + (size_t)(R0 + r0 + r) * OUT_F + c0) = o4;
    }

    const float4 a1v = *(const float4*)(a + c0);
    const float4 a2v = *(const float4*)(a + OUT_F + c0);
#pragma unroll
    for (int r = 0; r < 2; ++r) {
        float p1 = acc[r][0] * a1v.x + acc[r][1] * a1v.y + acc[r][2] * a1v.z + acc[r][3] * a1v.w;
        float p2 = acc[r][0] * a2v.x + acc[r][1] * a2v.y + acc[r][2] * a2v.z + acc[r][3] * a2v.w;
#pragma unroll
        for (int off = 16; off > 0; off >>= 1) {
            p1 += __shfl_xor(p1, off);
            p2 += __shfl_xor(p2, off);
        }
        if ((tid & 31) == 0) {
            s1[R0 + r0 + r] = p1;
            s2[R0 + r0 + r] = p2;
        }
    }
}

// ---------------------------------------------------------------------------
// Kernel 2: block-cooperative fused kernel. Block (4 waves) owns 4 CONSECUTIVE
// rows = one contiguous 128 KB region, and marches through it densely:
// iteration t reads chunk [t*4KB,(t+1)*4KB); wave w takes the w-th 1KB.
// -> 2048 long streams instead of 8192 scattered ones (DRAM row locality).
// Hits are ballot-compacted into per-(row, srcwave) LDS segments (running
// scalar counter; rt = t>>3 is monotonic, snapshot at row boundary).
// ONE barrier. Then wave w runs the R6-proven max-free softmax + split bf16
// gather + ELU on row (R0+w)'s 4 segments.
// grid 2048 x 256, 16.5 KB LDS -> 8 blocks/CU = 32 waves/CU.
// ---------------------------------------------------------------------------
__global__ __launch_bounds__(256, 8) void gat_fused(const float* __restrict__ adj,
                                                    const unsigned short* __restrict__ hb,
                                                    const float* __restrict__ s1,
                                                    const float* __restrict__ s2,
                                                    float* __restrict__ out) {
    const int tid  = threadIdx.x;
    const int wv   = tid >> 6;
    const int lane = tid & 63;
    const int R0   = blockIdx.x * 4;

    __shared__ int   jl[4][4][QCAP];    // [row][srcwave][idx]  8 KB
    __shared__ float el[4][4][QCAP];    // 8 KB
    __shared__ int   cntS[4][4];        // [row][srcwave]

    const f32x4* __restrict__ base4 = (const f32x4*)(adj + (size_t)R0 * N);
    const ull below = (1ull << lane) - 1ull;

    // ---- phase 1: 32 iterations over 128 KB contiguous, 4-deep ring
    int p = 0;
    f32x4 va[4], vb[4];
#pragma unroll
    for (int u = 0; u < 4; ++u) va[u] = base4[u * 256 + wv * 64 + lane];

    for (int b = 0; b < 8; ++b) {
        if (b < 7) {
#pragma unroll
            for (int u = 0; u < 4; ++u)
                vb[u] = base4[(b * 4 + 4 + u) * 256 + wv * 64 + lane];
        }
#pragma unroll
        for (int u = 0; u < 4; ++u) {
            const int t  = b * 4 + u;                    // 0..31
            const int rt = t >> 3;                       // local row 0..3
            const int jb = ((t & 7) * 256 + wv * 64 + lane) * 4;   // elem idx in row
            const float av[4] = {va[u].x, va[u].y, va[u].z, va[u].w};
#pragma unroll
            for (int c = 0; c < 4; ++c) {
                const bool hit = av[c] > 0.f;
                const ull m = __ballot(hit);
                if (m) {                                 // wave-uniform
                    const int bs = p;
                    p += __popcll(m);
                    if (hit) {
                        const int q = bs + __popcll(m & below);
                        if (q < QCAP) jl[rt][wv][q] = jb + c;
                    }
                }
            }
            if ((t & 7) == 7) {                          // row boundary
                if (lane == 0) cntS[rt][wv] = (p < QCAP ? p : QCAP);
                p = 0;
            }
        }
#pragma unroll
        for (int u = 0; u < 4; ++u) va[u] = vb[u];
    }
    __syncthreads();

    // ---- wave wv handles row R0 + wv (its 4 segments, src waves s=0..3)
    const int row = R0 + wv;
    const float si = s1[row];

    // phase 2: weights + denom (max-free, validated R10/R11)
    float dp = 0.f;
#pragma unroll
    for (int s = 0; s < 4; ++s) {
        const int ns = cntS[wv][s];
#pragma unroll
        for (int t = 0; t < 2; ++t) {
            const int l = lane + t * 64;
            if (l < ns) {
                float e = si + s2[jl[wv][s][l]];
                e = e > 0.f ? e : ALPHA * e;
                const float w = __expf(e);
                el[wv][s][l] = w;
                dp += w;
            }
        }
    }
#pragma unroll
    for (int off = 32; off > 0; off >>= 1) dp += __shfl_xor(dp, off);
    const float denom = dp;

    // phase 3: gather; lane halves take even/odd entries, 32 lanes x 4 cols
    const int half = lane >> 5;
    const int col4 = (lane & 31) * 4;
    float a0 = 0.f, a1 = 0.f, a2 = 0.f, a3 = 0.f;
#pragma unroll
    for (int s = 0; s < 4; ++s) {
        const int ns = cntS[wv][s];
#pragma unroll 2
        for (int l = half; l < ns; l += 2) {
            const float wgt = el[wv][s][l];
            const int j = jl[wv][s][l];
            const ushort4 hv = *(const ushort4*)(hb + (size_t)j * OUT_F + col4);
            a0 += wgt * bf2f(hv.x);
            a1 += wgt * bf2f(hv.y);
            a2 += wgt * bf2f(hv.z);
            a3 += wgt * bf2f(hv.w);
        }
    }
    a0 += __shfl_xor(a0, 32);
    a1 += __shfl_xor(a1, 32);
    a2 += __shfl_xor(a2, 32);
    a3 += __shfl_xor(a3, 32);

    if (half == 0) {
        const float r = 1.f / denom;
        float v0 = a0 * r, v1 = a1 * r, v2 = a2 * r, v3 = a3 * r;
        float4 o;
        o.x = v0 > 0.f ? v0 : (__expf(v0) - 1.f);
        o.y = v1 > 0.f ? v1 : (__expf(v1) - 1.f);
        o.z = v2 > 0.f ? v2 : (__expf(v2) - 1.f);
        o.w = v3 > 0.f ? v3 : (__expf(v3) - 1.f);
        *(float4*)(out + (size_t)row * OUT_F + col4) = o;
    }
}

// ---------------------------------------------------------------------------
extern "C" void kernel_launch(void* const* d_in, const int* in_sizes, int n_in,
                              void* d_out, int out_size, void* d_ws, size_t ws_size,
                              hipStream_t stream) {
    const float* x   = (const float*)d_in[0];   // (8192, 256)
    const float* adj = (const float*)d_in[1];   // (8192, 8192)
    const float* W   = (const float*)d_in[2];   // (256, 128)
    const float* a   = (const float*)d_in[3];   // (256, 1)
    float* out = (float*)d_out;                 // (8192, 128) fp32

    char* wsb = (char*)d_ws;
    unsigned short* hb = (unsigned short*)wsb;                    // 2 MB bf16 h
    float* s1 = (float*)(wsb + 2 * 1024 * 1024);                  // 32 KB
    float* s2 = s1 + N;                                           // 32 KB

    gemm_xw<<<N / 16, 256, 0, stream>>>(x, W, a, hb, s1, s2);
    gat_fused<<<2048, 256, 0, stream>>>(adj, hb, s1, s2, out);
}

// Round 14
// 70.649 us; speedup vs baseline: 1.1552x; 1.0288x over previous
//
#include <hip/hip_runtime.h>
#include <cstdint>
#include <cstddef>

#define N 8192
#define IN_F 256
#define OUT_F 128
#define ALPHA 0.2f
#define CAP 256
typedef unsigned long long ull;
typedef float f32x4 __attribute__((ext_vector_type(4)));

__device__ __forceinline__ float bf2f(unsigned short u) {
    return __uint_as_float(((unsigned)u) << 16);
}
__device__ __forceinline__ unsigned short f2bf(float f) {
    unsigned x = __float_as_uint(f);
    unsigned r = (x + 0x7FFFu + ((x >> 16) & 1u)) >> 16;   // round-nearest-even
    return (unsigned short)r;
}

// ---------------------------------------------------------------------------
// PRIMARY: one cooperative kernel, grid 2048 x 256 (= 32 waves/CU exactly).
//  blocks 0..511: 16-row gemm tile (BK=32, LDS unioned with scan lists) ->
//    hb/s1/s2 stores -> threadfence -> release atomicAdd(done).
//  ALL blocks: R6-proven per-wave scan of 4 rows (ballot compaction into
//    per-wave LDS lists) -> spin until done==512 (long satisfied; cooperative
//    launch guarantees co-residency => deadlock-free) -> max-free softmax ->
//    split bf16 gather -> ELU.
// The VALU/LDS-bound gemm hides entirely under the HBM-bound scan.
// LDS: max(gemm 18.94 KB, scan 8.25 KB) = 18.94 KB -> 8 blocks/CU fits.
// ---------------------------------------------------------------------------
__global__ __launch_bounds__(256, 8) void gat_all(const float* __restrict__ adj,
                                                  const float* __restrict__ x,
                                                  const float* __restrict__ W,
                                                  const float* __restrict__ a,
                                                  unsigned short* __restrict__ hb,
                                                  float* __restrict__ s1,
                                                  float* __restrict__ s2,
                                                  int* done,
                                                  float* __restrict__ out) {
    __shared__ __align__(16) float smem[4736];   // 18944 B union
    const int tid  = threadIdx.x;
    const int wv   = tid >> 6;
    const int lane = tid & 63;
    const int bid  = blockIdx.x;

    // ------------------------- gemm phase (blocks 0..511) -------------------
    if (bid < 512) {
        float* xsT = smem;          // [32][20] pad stride 20 = 640 floats
        float* wsh = smem + 640;    // [32][128] = 4096 floats
        const int R0 = bid * 16;
        const int r0 = (tid >> 5) * 2;   // 0..14
        const int c0 = (tid & 31) * 4;   // 0..124

        float acc[2][4];
#pragma unroll
        for (int r = 0; r < 2; ++r)
#pragma unroll
            for (int c = 0; c < 4; ++c) acc[r][c] = 0.f;

        for (int k0 = 0; k0 < IN_F; k0 += 32) {
            if (tid < 128) {
                const int r  = tid >> 3;     // 0..15
                const int k4 = tid & 7;      // 0..7
                const float4 v = *(const float4*)(x + (size_t)(R0 + r) * IN_F + k0 + k4 * 4);
                xsT[(k4 * 4 + 0) * 20 + r] = v.x;
                xsT[(k4 * 4 + 1) * 20 + r] = v.y;
                xsT[(k4 * 4 + 2) * 20 + r] = v.z;
                xsT[(k4 * 4 + 3) * 20 + r] = v.w;
            }
#pragma unroll
            for (int q = 0; q < 4; ++q) {
                const int f = tid + q * 256;  // 0..1023
                *(float4*)(wsh + f * 4) = *(const float4*)(W + (size_t)k0 * OUT_F + f * 4);
            }
            __syncthreads();
#pragma unroll 8
            for (int kk = 0; kk < 32; ++kk) {
                const float4 wv4 = *(const float4*)(wsh + kk * 128 + c0);
                const float2 xv  = *(const float2*)(xsT + kk * 20 + r0);
                acc[0][0] += xv.x * wv4.x; acc[0][1] += xv.x * wv4.y; acc[0][2] += xv.x * wv4.z; acc[0][3] += xv.x * wv4.w;
                acc[1][0] += xv.y * wv4.x; acc[1][1] += xv.y * wv4.y; acc[1][2] += xv.y * wv4.z; acc[1][3] += xv.y * wv4.w;
            }
            __syncthreads();
        }

#pragma unroll
        for (int r = 0; r < 2; ++r) {
            ushort4 o4;
            o4.x = f2bf(acc[r][0]); o4.y = f2bf(acc[r][1]);
            o4.z = f2bf(acc[r][2]); o4.w = f2bf(acc[r][3]);
            *(ushort4*)(hb + (size_t)(R0 + r0 + r) * OUT_F + c0) = o4;
        }
        const float4 a1v = *(const float4*)(a + c0);
        const float4 a2v = *(const float4*)(a + OUT_F + c0);
#pragma unroll
        for (int r = 0; r < 2; ++r) {
            float p1 = acc[r][0] * a1v.x + acc[r][1] * a1v.y + acc[r][2] * a1v.z + acc[r][3] * a1v.w;
            float p2 = acc[r][0] * a2v.x + acc[r][1] * a2v.y + acc[r][2] * a2v.z + acc[r][3] * a2v.w;
#pragma unroll
            for (int off = 16; off > 0; off >>= 1) {
                p1 += __shfl_xor(p1, off);
                p2 += __shfl_xor(p2, off);
            }
            if ((tid & 31) == 0) {
                s1[R0 + r0 + r] = p1;
                s2[R0 + r0 + r] = p2;
            }
        }
        __threadfence();            // each thread publishes its own stores
        __syncthreads();            // all threads' fences complete
        if (tid == 0)
            __hip_atomic_fetch_add(done, 1, __ATOMIC_RELEASE, __HIP_MEMORY_SCOPE_AGENT);
    }

    // ------------------------- scan phase (all blocks) ----------------------
    int*   jlw = ((int*)smem) + wv * CAP;       // overlay, per-wave segment
    float* elw = (smem + 1024) + wv * CAP;
    const int row = bid * 4 + wv;
    const f32x4* __restrict__ arow = (const f32x4*)(adj + (size_t)row * N);
    const ull below = (1ull << lane) - 1ull;

    int tot = 0;
    f32x4 va[4], vb[4];
#pragma unroll
    for (int u = 0; u < 4; ++u) va[u] = arow[lane + u * 64];

    for (int b = 0; b < 8; ++b) {
        if (b < 7) {
#pragma unroll
            for (int u = 0; u < 4; ++u) vb[u] = arow[lane + ((b + 1) * 4 + u) * 64];
        }
#pragma unroll
        for (int u = 0; u < 4; ++u) {
            const int jb = (((b * 4 + u) * 64) + lane) * 4;
            const float av[4] = {va[u].x, va[u].y, va[u].z, va[u].w};
#pragma unroll
            for (int c = 0; c < 4; ++c) {
                const bool hit = av[c] > 0.f;
                const ull m = __ballot(hit);
                if (m) {                       // wave-uniform
                    const int base = tot;
                    tot += __popcll(m);
                    if (hit) {
                        const int p = base + __popcll(m & below);
                        if (p < CAP) jlw[p] = jb + c;
                    }
                }
            }
        }
#pragma unroll
        for (int u = 0; u < 4; ++u) va[u] = vb[u];
    }
    const int n = tot < CAP ? tot : CAP;

    // ---- wait for all 512 gemm tiles (satisfied ~50us before arrival)
    while (__hip_atomic_load(done, __ATOMIC_ACQUIRE, __HIP_MEMORY_SCOPE_AGENT) < 512)
        __builtin_amdgcn_s_sleep(8);

    // ---- max-free softmax (validated R10-R13)
    const float si = s1[row];
    float dp = 0.f;
#pragma unroll
    for (int t = 0; t < 4; ++t) {
        const int l = lane + t * 64;
        if (l < n) {
            float e = si + s2[jlw[l]];
            e = e > 0.f ? e : ALPHA * e;
            const float w = __expf(e);
            elw[l] = w;
            dp += w;
        }
    }
#pragma unroll
    for (int off = 32; off > 0; off >>= 1) dp += __shfl_xor(dp, off);
    const float denom = dp;

    // ---- gather: lane halves take even/odd entries, 32 lanes x 4 cols
    const int half = lane >> 5;
    const int col4 = (lane & 31) * 4;
    float a0 = 0.f, a1 = 0.f, a2 = 0.f, a3 = 0.f;
#pragma unroll 4
    for (int l = half; l < n; l += 2) {
        const float wgt = elw[l];
        const int j = jlw[l];
        const ushort4 hv = *(const ushort4*)(hb + (size_t)j * OUT_F + col4);
        a0 += wgt * bf2f(hv.x);
        a1 += wgt * bf2f(hv.y);
        a2 += wgt * bf2f(hv.z);
        a3 += wgt * bf2f(hv.w);
    }
    a0 += __shfl_xor(a0, 32);
    a1 += __shfl_xor(a1, 32);
    a2 += __shfl_xor(a2, 32);
    a3 += __shfl_xor(a3, 32);

    if (half == 0) {
        const float r = 1.f / denom;
        float v0 = a0 * r, v1 = a1 * r, v2 = a2 * r, v3 = a3 * r;
        float4 o;
        o.x = v0 > 0.f ? v0 : (__expf(v0) - 1.f);
        o.y = v1 > 0.f ? v1 : (__expf(v1) - 1.f);
        o.z = v2 > 0.f ? v2 : (__expf(v2) - 1.f);
        o.w = v3 > 0.f ? v3 : (__expf(v3) - 1.f);
        *(float4*)(out + (size_t)row * OUT_F + col4) = o;
    }
}

// ---------------------------------------------------------------------------
// FALLBACK (if cooperative occupancy < 8 blocks/CU): proven R6 serial pair.
// ---------------------------------------------------------------------------
__global__ __launch_bounds__(256) void gemm_xw(const float* __restrict__ x,
                                               const float* __restrict__ W,
                                               const float* __restrict__ a,
                                               unsigned short* __restrict__ hb,
                                               float* __restrict__ s1,
                                               float* __restrict__ s2) {
    __shared__ __align__(16) float xsT[64 * 20];
    __shared__ __align__(16) float ws[64 * 128];
    const int tid = threadIdx.x;
    const int R0  = blockIdx.x * 16;
    const int r0  = (tid >> 5) * 2;
    const int c0  = (tid & 31) * 4;

    float acc[2][4];
#pragma unroll
    for (int r = 0; r < 2; ++r)
#pragma unroll
        for (int c = 0; c < 4; ++c) acc[r][c] = 0.f;

    for (int k0 = 0; k0 < IN_F; k0 += 64) {
        {
            const int r  = tid >> 4;
            const int k4 = tid & 15;
            const float4 v = *(const float4*)(x + (size_t)(R0 + r) * IN_F + k0 + k4 * 4);
            xsT[(k4 * 4 + 0) * 20 + r] = v.x;
            xsT[(k4 * 4 + 1) * 20 + r] = v.y;
            xsT[(k4 * 4 + 2) * 20 + r] = v.z;
            xsT[(k4 * 4 + 3) * 20 + r] = v.w;
        }
#pragma unroll
        for (int q = 0; q < 8; ++q) {
            const int f = tid + q * 256;
            *(float4*)(ws + f * 4) = *(const float4*)(W + (size_t)k0 * OUT_F + f * 4);
        }
        __syncthreads();
#pragma unroll 8
        for (int kk = 0; kk < 64; ++kk) {
            const float4 wv = *(const float4*)(ws + kk * 128 + c0);
            const float2 xv = *(const float2*)(xsT + kk * 20 + r0);
            acc[0][0] += xv.x * wv.x; acc[0][1] += xv.x * wv.y; acc[0][2] += xv.x * wv.z; acc[0][3] += xv.x * wv.w;
            acc[1][0] += xv.y * wv.x; acc[1][1] += xv.y * wv.y; acc[1][2] += xv.y * wv.z; acc[1][3] += xv.y * wv.w;
        }
        __syncthreads();
    }
#pragma unroll
    for (int r = 0; r < 2; ++r) {
        ushort4 o4;
        o4.x = f2bf(acc[r][0]); o4.y = f2bf(acc[r][1]);
        o4.z = f2bf(acc[r][2]); o4.w = f2bf(acc[r][3]);
        *(ushort4*)(hb + (size_t)(R0 + r0 + r) * OUT_F + c0) = o4;
    }
    const float4 a1v = *(const float4*)(a + c0);
    const float4 a2v = *(const float4*)(a + OUT_F + c0);
#pragma unroll
    for (int r = 0; r < 2; ++r) {
        float p1 = acc[r][0] * a1v.x + acc[r][1] * a1v.y + acc[r][2] * a1v.z + acc[r][3] * a1v.w;
        float p2 = acc[r][0] * a2v.x + acc[r][1] * a2v.y + acc[r][2] * a2v.z + acc[r][3] * a2v.w;
#pragma unroll
        for (int off = 16; off > 0; off >>= 1) {
            p1 += __shfl_xor(p1, off);
            p2 += __shfl_xor(p2, off);
        }
        if ((tid & 31) == 0) {
            s1[R0 + r0 + r] = p1;
            s2[R0 + r0 + r] = p2;
        }
    }
}

__global__ __launch_bounds__(256, 8) void gat_fused(const float* __restrict__ adj,
                                                    const unsigned short* __restrict__ hb,
                                                    const float* __restrict__ s1,
                                                    const float* __restrict__ s2,
                                                    float* __restrict__ out) {
    const int tid  = threadIdx.x;
    const int wv   = tid >> 6;
    const int lane = tid & 63;
    const int row  = blockIdx.x * 4 + wv;

    __shared__ int   jl[4][CAP];
    __shared__ float el[4][CAP];

    const f32x4* __restrict__ arow = (const f32x4*)(adj + (size_t)row * N);
    const ull below = (1ull << lane) - 1ull;

    int tot = 0;
    f32x4 va[4], vb[4];
#pragma unroll
    for (int u = 0; u < 4; ++u) va[u] = arow[lane + u * 64];

    for (int b = 0; b < 8; ++b) {
        if (b < 7) {
#pragma unroll
            for (int u = 0; u < 4; ++u) vb[u] = arow[lane + ((b + 1) * 4 + u) * 64];
        }
#pragma unroll
        for (int u = 0; u < 4; ++u) {
            const int jb = (((b * 4 + u) * 64) + lane) * 4;
            const float av[4] = {va[u].x, va[u].y, va[u].z, va[u].w};
#pragma unroll
            for (int c = 0; c < 4; ++c) {
                const bool hit = av[c] > 0.f;
                const ull m = __ballot(hit);
                if (m) {
                    const int base = tot;
                    tot += __popcll(m);
                    if (hit) {
                        const int p = base + __popcll(m & below);
                        if (p < CAP) jl[wv][p] = jb + c;
                    }
                }
            }
        }
#pragma unroll
        for (int u = 0; u < 4; ++u) va[u] = vb[u];
    }
    const int n = tot < CAP ? tot : CAP;

    const float si = s1[row];
    float dp = 0.f;
#pragma unroll
    for (int t = 0; t < 4; ++t) {
        const int l = lane + t * 64;
        if (l < n) {
            float e = si + s2[jl[wv][l]];
            e = e > 0.f ? e : ALPHA * e;
            const float w = __expf(e);
            el[wv][l] = w;
            dp += w;
        }
    }
#pragma unroll
    for (int off = 32; off > 0; off >>= 1) dp += __shfl_xor(dp, off);
    const float denom = dp;

    const int half = lane >> 5;
    const int col4 = (lane & 31) * 4;
    float a0 = 0.f, a1 = 0.f, a2 = 0.f, a3 = 0.f;
#pragma unroll 4
    for (int l = half; l < n; l += 2) {
        const float wgt = el[wv][l];
        const int j = jl[wv][l];
        const ushort4 hv = *(const ushort4*)(hb + (size_t)j * OUT_F + col4);
        a0 += wgt * bf2f(hv.x);
        a1 += wgt * bf2f(hv.y);
        a2 += wgt * bf2f(hv.z);
        a3 += wgt * bf2f(hv.w);
    }
    a0 += __shfl_xor(a0, 32);
    a1 += __shfl_xor(a1, 32);
    a2 += __shfl_xor(a2, 32);
    a3 += __shfl_xor(a3, 32);

    if (half == 0) {
        const float r = 1.f / denom;
        float v0 = a0 * r, v1 = a1 * r, v2 = a2 * r, v3 = a3 * r;
        float4 o;
        o.x = v0 > 0.f ? v0 : (__expf(v0) - 1.f);
        o.y = v1 > 0.f ? v1 : (__expf(v1) - 1.f);
        o.z = v2 > 0.f ? v2 : (__expf(v2) - 1.f);
        o.w = v3 > 0.f ? v3 : (__expf(v3) - 1.f);
        *(float4*)(out + (size_t)row * OUT_F + col4) = o;
    }
}

// ---------------------------------------------------------------------------
extern "C" void kernel_launch(void* const* d_in, const int* in_sizes, int n_in,
                              void* d_out, int out_size, void* d_ws, size_t ws_size,
                              hipStream_t stream) {
    const float* x   = (const float*)d_in[0];   // (8192, 256)
    const float* adj = (const float*)d_in[1];   // (8192, 8192)
    const float* W   = (const float*)d_in[2];   // (256, 128)
    const float* a   = (const float*)d_in[3];   // (256, 1)
    float* out = (float*)d_out;                 // (8192, 128) fp32

    char* wsb = (char*)d_ws;
    unsigned short* hb = (unsigned short*)wsb;                    // 2 MB bf16 h
    float* s1 = (float*)(wsb + 2 * 1024 * 1024);                  // 32 KB
    float* s2 = s1 + N;                                           // 32 KB
    int* done = (int*)(wsb + 2 * 1024 * 1024 + 64 * 1024);        // 4 B flag

    // Cooperative path requires full co-residency (8 blocks/CU x 256 CUs).
    int nb = 0;
    (void)hipOccupancyMaxActiveBlocksPerMultiprocessor(&nb, gat_all, 256, 0);
    if (nb >= 8) {
        hipMemsetAsync(done, 0, sizeof(int), stream);
        void* args[] = {(void*)&adj, (void*)&x, (void*)&W, (void*)&a,
                        (void*)&hb, (void*)&s1, (void*)&s2, (void*)&done, (void*)&out};
        hipLaunchCooperativeKernel((const void*)gat_all, dim3(2048), dim3(256),
                                   args, 0, stream);
    } else {
        gemm_xw<<<N / 16, 256, 0, stream>>>(x, W, a, hb, s1, s2);
        gat_fused<<<2048, 256, 0, stream>>>(adj, hb, s1, s2, out);
    }
}